// Round 7
// baseline (477.216 us; speedup 1.0000x reference)
//
#include <hip/hip_runtime.h>
#include <hip/hip_cooperative_groups.h>

namespace cg = cooperative_groups;

#define NG 4096
#define RELAX 0.1875f
#define KEEPTH -5.2933049f   // logit(0.005): sigmoid(o)>0.005 <=> o>KEEPTH
#define CAP 2048
#define CTHREADS 512
#define CBLOCKS 1024
#define CHUNK 512

__device__ __forceinline__ float linf(int i) { return -1.0f + (2.0f/63.0f)*(float)i; }
// center-first axis permutation (fallback eval ordering)
__device__ __forceinline__ int cperm(int i) { return (i & 1) ? 7 + ((i+1)>>1) : 7 - (i>>1); }

// ---- shared device helpers (verified math, r3-r6) ----
template<int T>
__device__ __forceinline__ float4 block_minmax_cs(
    const float4* __restrict__ xyz4, const float4* __restrict__ op4,
    int tid, float (*s_r)[6])
{
  float mn0=1e10f, mn1=1e10f, mn2=1e10f;
  float mx0=-1e10f, mx1=-1e10f, mx2=-1e10f;
  #pragma unroll
  for (int t = 0; t < NG/4/T; ++t) {
    const int G = t*T + tid;             // group of 4 gaussians
    float4 v0 = xyz4[3*G+0], v1 = xyz4[3*G+1], v2 = xyz4[3*G+2];
    float4 oo = op4[G];
    if (oo.x > KEEPTH) { mn0=fminf(mn0,v0.x); mx0=fmaxf(mx0,v0.x);
                         mn1=fminf(mn1,v0.y); mx1=fmaxf(mx1,v0.y);
                         mn2=fminf(mn2,v0.z); mx2=fmaxf(mx2,v0.z); }
    if (oo.y > KEEPTH) { mn0=fminf(mn0,v0.w); mx0=fmaxf(mx0,v0.w);
                         mn1=fminf(mn1,v1.x); mx1=fmaxf(mx1,v1.x);
                         mn2=fminf(mn2,v1.y); mx2=fmaxf(mx2,v1.y); }
    if (oo.z > KEEPTH) { mn0=fminf(mn0,v1.z); mx0=fmaxf(mx0,v1.z);
                         mn1=fminf(mn1,v1.w); mx1=fmaxf(mx1,v1.w);
                         mn2=fminf(mn2,v2.x); mx2=fmaxf(mx2,v2.x); }
    if (oo.w > KEEPTH) { mn0=fminf(mn0,v2.y); mx0=fmaxf(mx0,v2.y);
                         mn1=fminf(mn1,v2.z); mx1=fmaxf(mx1,v2.z);
                         mn2=fminf(mn2,v2.w); mx2=fmaxf(mx2,v2.w); }
  }
  #pragma unroll
  for (int s = 1; s < 64; s <<= 1) {
    mn0 = fminf(mn0, __shfl_xor(mn0, s)); mx0 = fmaxf(mx0, __shfl_xor(mx0, s));
    mn1 = fminf(mn1, __shfl_xor(mn1, s)); mx1 = fmaxf(mx1, __shfl_xor(mx1, s));
    mn2 = fminf(mn2, __shfl_xor(mn2, s)); mx2 = fmaxf(mx2, __shfl_xor(mx2, s));
  }
  if ((tid & 63) == 0) {
    const int w = tid >> 6;
    s_r[w][0]=mn0; s_r[w][1]=mn1; s_r[w][2]=mn2;
    s_r[w][3]=mx0; s_r[w][4]=mx1; s_r[w][5]=mx2;
  }
  __syncthreads();
  mn0 = s_r[0][0]; mn1 = s_r[0][1]; mn2 = s_r[0][2];
  mx0 = s_r[0][3]; mx1 = s_r[0][4]; mx2 = s_r[0][5];
  #pragma unroll
  for (int w = 1; w < T/64; ++w) {
    mn0 = fminf(mn0, s_r[w][0]); mn1 = fminf(mn1, s_r[w][1]); mn2 = fminf(mn2, s_r[w][2]);
    mx0 = fmaxf(mx0, s_r[w][3]); mx1 = fmaxf(mx1, s_r[w][4]); mx2 = fmaxf(mx2, s_r[w][5]);
  }
  return make_float4((mn0+mx0)*0.5f, (mn1+mx1)*0.5f, (mn2+mx2)*0.5f,
                     1.8f/fmaxf(mx0-mn0, fmaxf(mx1-mn1, mx2-mn2)));
}

__device__ __forceinline__ void transform_one(
    const float* __restrict__ xyz, const float* __restrict__ scal,
    const float* __restrict__ rot, const float* __restrict__ opac,
    int g, float cx, float cy, float cz, float sc, float4* __restrict__ rec)
{
  float o = opac[g];
  float sig = 1.0f/(1.0f + __expf(-o));
  float opa = (sig > 0.005f) ? sig : 0.0f;
  float xs = (xyz[3*g+0]-cx)*sc;
  float ys = (xyz[3*g+1]-cy)*sc;
  float zs = (xyz[3*g+2]-cz)*sc;
  float sdx = __expf(scal[3*g+0])*sc;
  float sdy = __expf(scal[3*g+1])*sc;
  float sdz = __expf(scal[3*g+2])*sc;
  float qr=rot[4*g+0], qx=rot[4*g+1], qy=rot[4*g+2], qz=rot[4*g+3];
  float qn = 1.0f/sqrtf(qr*qr+qx*qx+qy*qy+qz*qz);
  qr*=qn; qx*=qn; qy*=qn; qz*=qn;
  float R00 = 1.0f-2.0f*(qy*qy+qz*qz), R01 = 2.0f*(qx*qy-qr*qz), R02 = 2.0f*(qx*qz+qr*qy);
  float R10 = 2.0f*(qx*qy+qr*qz), R11 = 1.0f-2.0f*(qx*qx+qz*qz), R12 = 2.0f*(qy*qz-qr*qx);
  float R20 = 2.0f*(qx*qz-qr*qy), R21 = 2.0f*(qy*qz+qr*qx), R22 = 1.0f-2.0f*(qx*qx+qy*qy);
  float L00=R00*sdx, L01=R01*sdy, L02=R02*sdz;
  float L10=R10*sdx, L11=R11*sdy, L12=R12*sdz;
  float L20=R20*sdx, L21=R21*sdy, L22=R22*sdz;
  float a = L00*L00+L01*L01+L02*L02;
  float bb= L00*L10+L01*L11+L02*L12;
  float cc= L00*L20+L01*L21+L02*L22;
  float d = L10*L10+L11*L11+L12*L12;
  float e = L10*L20+L11*L21+L12*L22;
  float f = L20*L20+L21*L21+L22*L22;
  float det = a*d*f + 2.0f*e*cc*bb - e*e*a - cc*cc*d - bb*bb*f + 1e-24f;
  float idt = 1.0f/det;
  float ia=(d*f-e*e)*idt, ib=(e*cc-bb*f)*idt, ic=(e*bb-cc*d)*idt;
  float id=(a*f-cc*cc)*idt, ie=(bb*cc-e*a)*idt, iff=(a*d-bb*bb)*idt;
  rec[3*g+0] = make_float4(xs, ys, zs, opa);
  rec[3*g+1] = make_float4(-0.5f*ia, -ib, -ic, -0.5f*id);
  rec[3*g+2] = make_float4(-ie, -0.5f*iff, 0.0f, 0.0f);
}

template<int T>
__device__ __forceinline__ void bin_column(
    const float4* __restrict__ xyz4, const float4* __restrict__ op4,
    int c, int tid, float cx, float cy, float cz, float sc,
    int* s_cnt, unsigned short* __restrict__ binidx)
{
  const int bi = c >> 4, bj = c & 15;
  const float vminx = linf(bi*4) - RELAX, vmaxx = linf(bi*4+3) + RELAX;
  const float vminy = linf(bj*4) - RELAX, vmaxy = linf(bj*4+3) + RELAX;
  #pragma unroll
  for (int t = 0; t < NG/4/T; ++t) {
    const int G = t*T + tid;
    float4 v0 = xyz4[3*G+0], v1 = xyz4[3*G+1], v2 = xyz4[3*G+2];
    float4 oo = op4[G];
    float gx[4] = {v0.x, v0.w, v1.z, v2.y};
    float gy[4] = {v0.y, v1.x, v1.w, v2.z};
    float gz[4] = {v0.z, v1.y, v2.x, v2.w};
    float go[4] = {oo.x, oo.y, oo.z, oo.w};
    #pragma unroll
    for (int u = 0; u < 4; ++u) {
      if (!(go[u] > KEEPTH)) continue;
      float xs = (gx[u]-cx)*sc;
      float ys = (gy[u]-cy)*sc;
      float zs = (gz[u]-cz)*sc;
      if (xs > vminx && xs < vmaxx && ys > vminy && ys < vmaxy) {
        int klo = (int)floorf(((zs + 0.8125f)*31.5f - 3.0f)*0.25f) - 1;
        int khi = (int)floorf((zs + 1.1875f)*7.875f) + 1;
        klo = max(klo, 0); khi = min(khi, 15);
        for (int bk = klo; bk <= khi; ++bk) {
          float lo = linf(bk*4) - RELAX, hi = linf(bk*4+3) + RELAX;
          if (zs > lo && zs < hi) {
            int slot = atomicAdd(&s_cnt[bk], 1);
            if (slot < CAP)
              binidx[(size_t)((c<<4) + bk)*CAP + slot] = (unsigned short)(4*G+u);
          }
        }
      }
    }
  }
}

// ======================================================================
// The cooperative kernel: 1024 blocks x 512 thr, all resident (4/CU).
// prep (minmax+transform+bin+out-zero) -> grid.sync -> prefix-sum ->
// grid.sync -> record-balanced eval (each block ~total/1024 records).
// ======================================================================
__global__ __launch_bounds__(CTHREADS, 8) void gm_all(
    const float* __restrict__ xyz, const float* __restrict__ scal,
    const float* __restrict__ rot, const float* __restrict__ opac,
    float4* __restrict__ rec, int* __restrict__ bincnt,
    int* __restrict__ pfx, unsigned short* __restrict__ binidx,
    float* __restrict__ out)
{
  __shared__ float  s_r[8][6];
  __shared__ int    s_cnt[16];
  __shared__ int    s_w[8];
  __shared__ float4 s_g[CHUNK*3];       // 24 KB
  __shared__ float  s_acc[CTHREADS];    //  2 KB
  cg::grid_group grid = cg::this_grid();
  const int tid = threadIdx.x;
  const int b   = blockIdx.x;
  const float4* xyz4 = (const float4*)xyz;
  const float4* op4  = (const float4*)opac;

  // ---- zero out (1 MB, needed for atomicAdd merge) ----
  {
    const int gid = b*CTHREADS + tid;
    if (gid < 65536) ((float4*)out)[gid] = make_float4(0,0,0,0);
  }

  // ---- minmax (redundant per block, L2-resident) ----
  const float4 cs = block_minmax_cs<CTHREADS>(xyz4, op4, tid, s_r);
  const float cx = cs.x, cy = cs.y, cz = cs.z, sc = cs.w;

  // ---- transform my 4 gaussians ----
  if (tid < 4) transform_one(xyz, scal, rot, opac, b*4+tid, cx, cy, cz, sc, rec);

  // ---- bin: blocks b%4==0 own column c=b>>2 (256 columns) ----
  if ((b & 3) == 0) {
    const int c = b >> 2;
    if (tid < 16) s_cnt[tid] = 0;
    __syncthreads();
    bin_column<CTHREADS>(xyz4, op4, c, tid, cx, cy, cz, sc, s_cnt, binidx);
    __syncthreads();
    if (tid < 16) bincnt[(c<<4) + tid] = min(s_cnt[tid], CAP);
  }

  grid.sync();

  // ---- prefix sum over 4096 bin counts (block 0) ----
  if (b == 0) {
    int v[8]; int s = 0;
    #pragma unroll
    for (int i = 0; i < 8; ++i) { v[i] = bincnt[tid*8 + i]; s += v[i]; }
    const int lane = tid & 63, w = tid >> 6;
    int inc = s;
    #pragma unroll
    for (int d = 1; d < 64; d <<= 1) {
      int t2 = __shfl_up(inc, d);
      if (lane >= d) inc += t2;
    }
    if (lane == 63) s_w[w] = inc;
    __syncthreads();
    int wb = 0;
    for (int i = 0; i < w; ++i) wb += s_w[i];
    int run = wb + inc - s;               // exclusive prefix of my 8
    #pragma unroll
    for (int i = 0; i < 8; ++i) { pfx[tid*8 + i] = run; run += v[i]; }
    if (tid == CTHREADS-1) pfx[4096] = run;
  }

  grid.sync();

  // ---- record-balanced eval ----
  const int total = pfx[4096];
  if (total == 0) return;
  const int lo = (int)(((long)b     * total) >> 10);
  const int hi = (int)(((long)(b+1) * total) >> 10);
  if (lo >= hi) return;

  int blo = 0, bhi = 4096;                // max bin with pfx[bin] <= lo
  while (bhi - blo > 1) { int mid = (blo + bhi) >> 1; if (pfx[mid] <= lo) blo = mid; else bhi = mid; }
  int bin = blo;

  const int p = tid & 63, part = tid >> 6;   // part 0..7
  const int sx = p >> 4, sy = (p >> 2) & 3, sz = p & 3;

  int r = lo;
  while (r < hi) {
    while (pfx[bin+1] <= r) ++bin;
    const int segEnd = min(hi, pfx[bin+1]);
    const int bi = bin >> 8, bj = (bin >> 4) & 15, bk = bin & 15;
    const float ptx = linf(bi*4+sx), pty = linf(bj*4+sy), ptz = linf(bk*4+sz);
    const unsigned short* lst = binidx + (size_t)bin*CAP + (r - pfx[bin]);
    const int n = segEnd - r;
    float acc = 0.0f;

    for (int c0 = 0; c0 < n; c0 += CHUNK) {
      __syncthreads();
      const int lim = min(n - c0, CHUNK);
      if (tid < lim) {
        const int g = lst[c0 + tid];
        s_g[3*tid+0] = rec[3*g+0];
        s_g[3*tid+1] = rec[3*g+1];
        s_g[3*tid+2] = rec[3*g+2];
      }
      __syncthreads();
      #pragma unroll 4
      for (int j = part; j < lim; j += 8) {
        float4 P  = s_g[3*j+0];
        float4 I0 = s_g[3*j+1];
        float4 I1 = s_g[3*j+2];
        float px = ptx - P.x, py = pty - P.y, pz = ptz - P.z;
        float power = px*px*I0.x + py*py*I0.w + pz*pz*I1.y
                    + px*py*I0.y + px*pz*I0.z + py*pz*I1.x;
        power = (power > 0.0f) ? -1e10f : power;   // branchless
        acc += P.w * __expf(power);
      }
    }

    __syncthreads();
    s_acc[tid] = acc;
    __syncthreads();
    if (tid < 64) {
      float v = 0.0f;
      #pragma unroll
      for (int w2 = 0; w2 < 8; ++w2) v += s_acc[tid + w2*64];
      atomicAdd(&out[(bi*4+sx)*4096 + (bj*4+sy)*64 + (bk*4+sz)], v);
    }
    r = segEnd;
  }
}

// ======================================================================
// Fallback A (no coop): r6-verified prep + r1-structure 512-thr eval
// ======================================================================
__global__ __launch_bounds__(256) void gm_prep_bin256(
    const float* __restrict__ xyz, const float* __restrict__ scal,
    const float* __restrict__ rot, const float* __restrict__ opac,
    float4* __restrict__ rec,
    int* __restrict__ bincnt, unsigned short* __restrict__ binidx)
{
  __shared__ float s_r[8][6];
  __shared__ int   s_cnt[16];
  const int tid = threadIdx.x;
  const int b   = blockIdx.x;            // column bi*16+bj
  const float4* xyz4 = (const float4*)xyz;
  const float4* op4  = (const float4*)opac;
  if (tid < 16) s_cnt[tid] = 0;
  const float4 cs = block_minmax_cs<256>(xyz4, op4, tid, s_r);
  const float cx = cs.x, cy = cs.y, cz = cs.z, sc = cs.w;
  if (tid < 16) transform_one(xyz, scal, rot, opac, b*16+tid, cx, cy, cz, sc, rec);
  __syncthreads();
  bin_column<256>(xyz4, op4, b, tid, cx, cy, cz, sc, s_cnt, binidx);
  __syncthreads();
  if (tid < 16) bincnt[(b<<4) + tid] = min(s_cnt[tid], CAP);
}

__global__ __launch_bounds__(512) void gm_eval512(
    const float4* __restrict__ rec,
    const int* __restrict__ bincnt, const unsigned short* __restrict__ binidx,
    float* __restrict__ out)
{
  __shared__ float4 s_g[512*3];
  __shared__ float  s_acc[512];
  const int tid = threadIdx.x;
  const int b = blockIdx.x;
  const int bi = cperm(b >> 8), bj = cperm((b >> 4) & 15), bk = cperm(b & 15);
  const int bin = (bi*16 + bj)*16 + bk;
  const int p    = tid & 63;
  const int part = tid >> 6;
  const int sx = p >> 4, sy = (p >> 2) & 3, sz = p & 3;
  const int obase = (bi*4+sx)*4096 + (bj*4+sy)*64 + (bk*4+sz);
  const int n = min(bincnt[bin], CAP);
  if (n == 0) { if (tid < 64) out[obase] = 0.0f; return; }
  const float ptx = linf(bi*4+sx), pty = linf(bj*4+sy), ptz = linf(bk*4+sz);
  const unsigned short* mylist = binidx + (size_t)bin*CAP;
  float acc = 0.0f;
  for (int c0 = 0; c0 < n; c0 += 512) {
    __syncthreads();
    const int lim = min(n - c0, 512);
    if (tid < lim) {
      const int g = mylist[c0 + tid];
      s_g[3*tid+0] = rec[3*g+0];
      s_g[3*tid+1] = rec[3*g+1];
      s_g[3*tid+2] = rec[3*g+2];
    }
    __syncthreads();
    #pragma unroll 4
    for (int j = part; j < lim; j += 8) {
      float4 P  = s_g[3*j+0];
      float4 I0 = s_g[3*j+1];
      float4 I1 = s_g[3*j+2];
      float px = ptx - P.x, py = pty - P.y, pz = ptz - P.z;
      float power = px*px*I0.x + py*py*I0.w + pz*pz*I1.y
                  + px*py*I0.y + px*pz*I0.z + py*pz*I1.x;
      power = (power > 0.0f) ? -1e10f : power;
      acc += P.w * __expf(power);
    }
  }
  __syncthreads();
  s_acc[tid] = acc;
  __syncthreads();
  if (tid < 64) {
    float v = 0.0f;
    #pragma unroll
    for (int w = 0; w < 8; ++w) v += s_acc[tid + w*64];
    out[obase] = v;
  }
}

// ======================================================================
// Fallback B (tiny ws): fully fused, zero-workspace (r4/r6-verified)
// ======================================================================
__global__ __launch_bounds__(256) void gm_fused_nows(
    const float* __restrict__ xyz, const float* __restrict__ scal,
    const float* __restrict__ rot, const float* __restrict__ opac,
    float* __restrict__ out)
{
  __shared__ float s_r[8][6];
  __shared__ float4 s_g[256*3];
  __shared__ float  s_acc[256];
  __shared__ int    s_cnt;
  const int tid = threadIdx.x;
  const float4* xyz4 = (const float4*)xyz;
  const float4* op4  = (const float4*)opac;
  if (tid == 0) s_cnt = 0;
  const float4 cs = block_minmax_cs<256>(xyz4, op4, tid, s_r);
  const float cx = cs.x, cy = cs.y, cz = cs.z, sc = cs.w;

  const int bin = blockIdx.x;
  const int bi = bin >> 8, bj = (bin >> 4) & 15, bk = bin & 15;
  const float vminx = linf(bi*4) - RELAX, vmaxx = linf(bi*4+3) + RELAX;
  const float vminy = linf(bj*4) - RELAX, vmaxy = linf(bj*4+3) + RELAX;
  const float vminz = linf(bk*4) - RELAX, vmaxz = linf(bk*4+3) + RELAX;
  const int p    = tid & 63;
  const int part = tid >> 6;
  const int sx = p >> 4, sy = (p >> 2) & 3, sz = p & 3;
  const float ptx = linf(bi*4+sx), pty = linf(bj*4+sy), ptz = linf(bk*4+sz);
  float acc = 0.0f;
  __syncthreads();

  for (int c0 = 0; c0 < NG; c0 += 256) {
    const int g = c0 + tid;
    float o = opac[g];
    bool pass = false;
    float xs=0, ys=0, zs=0, sig=0;
    if (o > KEEPTH) {
      sig = 1.0f/(1.0f + __expf(-o));
      xs = (xyz[3*g+0]-cx)*sc;
      ys = (xyz[3*g+1]-cy)*sc;
      zs = (xyz[3*g+2]-cz)*sc;
      pass = xs > vminx && xs < vmaxx &&
             ys > vminy && ys < vmaxy &&
             zs > vminz && zs < vmaxz;
    }
    if (pass) {
      float sdx = __expf(scal[3*g+0])*sc;
      float sdy = __expf(scal[3*g+1])*sc;
      float sdz = __expf(scal[3*g+2])*sc;
      float qr=rot[4*g+0], qx=rot[4*g+1], qy=rot[4*g+2], qz=rot[4*g+3];
      float qn = 1.0f/sqrtf(qr*qr+qx*qx+qy*qy+qz*qz);
      qr*=qn; qx*=qn; qy*=qn; qz*=qn;
      float R00 = 1.0f-2.0f*(qy*qy+qz*qz), R01 = 2.0f*(qx*qy-qr*qz), R02 = 2.0f*(qx*qz+qr*qy);
      float R10 = 2.0f*(qx*qy+qr*qz), R11 = 1.0f-2.0f*(qx*qx+qz*qz), R12 = 2.0f*(qy*qz-qr*qx);
      float R20 = 2.0f*(qx*qz-qr*qy), R21 = 2.0f*(qy*qz+qr*qx), R22 = 1.0f-2.0f*(qx*qx+qy*qy);
      float L00=R00*sdx, L01=R01*sdy, L02=R02*sdz;
      float L10=R10*sdx, L11=R11*sdy, L12=R12*sdz;
      float L20=R20*sdx, L21=R21*sdy, L22=R22*sdz;
      float a = L00*L00+L01*L01+L02*L02;
      float bb= L00*L10+L01*L11+L02*L12;
      float cc= L00*L20+L01*L21+L02*L22;
      float d = L10*L10+L11*L11+L12*L12;
      float e = L10*L20+L11*L21+L12*L22;
      float f = L20*L20+L21*L21+L22*L22;
      float det = a*d*f + 2.0f*e*cc*bb - e*e*a - cc*cc*d - bb*bb*f + 1e-24f;
      float idt = 1.0f/det;
      float ia=(d*f-e*e)*idt, ib=(e*cc-bb*f)*idt, ic=(e*bb-cc*d)*idt;
      float id=(a*f-cc*cc)*idt, ie=(bb*cc-e*a)*idt, iff=(a*d-bb*bb)*idt;
      int slot = atomicAdd(&s_cnt, 1);
      s_g[3*slot+0] = make_float4(xs, ys, zs, sig);
      s_g[3*slot+1] = make_float4(-0.5f*ia, -ib, -ic, -0.5f*id);
      s_g[3*slot+2] = make_float4(-ie, -0.5f*iff, 0.0f, 0.0f);
    }
    __syncthreads();
    const int n = s_cnt;
    #pragma unroll 4
    for (int j = part; j < n; j += 4) {
      float4 P  = s_g[3*j+0];
      float4 I0 = s_g[3*j+1];
      float4 I1 = s_g[3*j+2];
      float px = ptx - P.x, py = pty - P.y, pz = ptz - P.z;
      float power = px*px*I0.x + py*py*I0.w + pz*pz*I1.y
                  + px*py*I0.y + px*pz*I0.z + py*pz*I1.x;
      power = (power > 0.0f) ? -1e10f : power;
      acc += P.w * __expf(power);
    }
    __syncthreads();
    if (tid == 0) s_cnt = 0;
    __syncthreads();
  }
  s_acc[tid] = acc;
  __syncthreads();
  if (tid < 64) {
    float v = s_acc[tid] + s_acc[tid+64] + s_acc[tid+128] + s_acc[tid+192];
    out[(bi*4+sx)*4096 + (bj*4+sy)*64 + (bk*4+sz)] = v;
  }
}

extern "C" void kernel_launch(void* const* d_in, const int* in_sizes, int n_in,
                              void* d_out, int out_size, void* d_ws, size_t ws_size,
                              hipStream_t stream) {
  const float* xyz  = (const float*)d_in[0];
  const float* scal = (const float*)d_in[1];
  const float* rot  = (const float*)d_in[2];
  const float* opac = (const float*)d_in[3];
  float* out = (float*)d_out;
  char* ws = (char*)d_ws;
  float4* rec    = (float4*)ws;                       // 192 KB
  int*    bincnt = (int*)(ws + 196608);               //  16 KB
  int*    pfx    = (int*)(ws + 212992);               //  ~16 KB (4097 ints)
  unsigned short* binidx = (unsigned short*)(ws + 229632);
  const size_t needed = 229632 + (size_t)4096*CAP*2;  // ~17 MB

  if (ws_size >= needed) {
    void* args[9] = { (void*)&xyz, (void*)&scal, (void*)&rot, (void*)&opac,
                      (void*)&rec, (void*)&bincnt, (void*)&pfx, (void*)&binidx,
                      (void*)&out };
    hipError_t e = hipLaunchCooperativeKernel((const void*)gm_all,
                                              dim3(CBLOCKS), dim3(CTHREADS),
                                              args, 0, stream);
    if (e == hipSuccess) return;
    (void)hipGetLastError();            // clear sticky error, use fallback
    gm_prep_bin256<<<256, 256, 0, stream>>>(xyz, scal, rot, opac,
                                            rec, bincnt, binidx);
    gm_eval512<<<4096, 512, 0, stream>>>(rec, bincnt, binidx, out);
  } else {
    gm_fused_nows<<<4096, 256, 0, stream>>>(xyz, scal, rot, opac, out);
  }
}

// Round 8
// 145.811 us; speedup vs baseline: 3.2728x; 3.2728x over previous
//
#include <hip/hip_runtime.h>

#define NG 4096
#define RELAX 0.1875f
#define KEEPTH -5.2933049f   // logit(0.005): sigmoid(o)>0.005 <=> o>KEEPTH
#define CAP 2048

__device__ __forceinline__ float linf(int i) { return -1.0f + (2.0f/63.0f)*(float)i; }
// center-first axis permutation: {7,8,6,9,5,10,4,11,3,12,2,13,1,14,0,15}
__device__ __forceinline__ int cperm(int i) { return (i & 1) ? 7 + ((i+1)>>1) : 7 - (i>>1); }

// ---- shared device helpers (math verified r3-r7) ----
template<int T>
__device__ __forceinline__ float4 block_minmax_cs(
    const float4* __restrict__ xyz4, const float4* __restrict__ op4,
    int tid, float (*s_r)[6])
{
  float mn0=1e10f, mn1=1e10f, mn2=1e10f;
  float mx0=-1e10f, mx1=-1e10f, mx2=-1e10f;
  #pragma unroll
  for (int t = 0; t < NG/4/T; ++t) {
    const int G = t*T + tid;             // group of 4 gaussians
    float4 v0 = xyz4[3*G+0], v1 = xyz4[3*G+1], v2 = xyz4[3*G+2];
    float4 oo = op4[G];
    if (oo.x > KEEPTH) { mn0=fminf(mn0,v0.x); mx0=fmaxf(mx0,v0.x);
                         mn1=fminf(mn1,v0.y); mx1=fmaxf(mx1,v0.y);
                         mn2=fminf(mn2,v0.z); mx2=fmaxf(mx2,v0.z); }
    if (oo.y > KEEPTH) { mn0=fminf(mn0,v0.w); mx0=fmaxf(mx0,v0.w);
                         mn1=fminf(mn1,v1.x); mx1=fmaxf(mx1,v1.x);
                         mn2=fminf(mn2,v1.y); mx2=fmaxf(mx2,v1.y); }
    if (oo.z > KEEPTH) { mn0=fminf(mn0,v1.z); mx0=fmaxf(mx0,v1.z);
                         mn1=fminf(mn1,v1.w); mx1=fmaxf(mx1,v1.w);
                         mn2=fminf(mn2,v2.x); mx2=fmaxf(mx2,v2.x); }
    if (oo.w > KEEPTH) { mn0=fminf(mn0,v2.y); mx0=fmaxf(mx0,v2.y);
                         mn1=fminf(mn1,v2.z); mx1=fmaxf(mx1,v2.z);
                         mn2=fminf(mn2,v2.w); mx2=fmaxf(mx2,v2.w); }
  }
  #pragma unroll
  for (int s = 1; s < 64; s <<= 1) {
    mn0 = fminf(mn0, __shfl_xor(mn0, s)); mx0 = fmaxf(mx0, __shfl_xor(mx0, s));
    mn1 = fminf(mn1, __shfl_xor(mn1, s)); mx1 = fmaxf(mx1, __shfl_xor(mx1, s));
    mn2 = fminf(mn2, __shfl_xor(mn2, s)); mx2 = fmaxf(mx2, __shfl_xor(mx2, s));
  }
  if ((tid & 63) == 0) {
    const int w = tid >> 6;
    s_r[w][0]=mn0; s_r[w][1]=mn1; s_r[w][2]=mn2;
    s_r[w][3]=mx0; s_r[w][4]=mx1; s_r[w][5]=mx2;
  }
  __syncthreads();
  mn0 = s_r[0][0]; mn1 = s_r[0][1]; mn2 = s_r[0][2];
  mx0 = s_r[0][3]; mx1 = s_r[0][4]; mx2 = s_r[0][5];
  #pragma unroll
  for (int w = 1; w < T/64; ++w) {
    mn0 = fminf(mn0, s_r[w][0]); mn1 = fminf(mn1, s_r[w][1]); mn2 = fminf(mn2, s_r[w][2]);
    mx0 = fmaxf(mx0, s_r[w][3]); mx1 = fmaxf(mx1, s_r[w][4]); mx2 = fmaxf(mx2, s_r[w][5]);
  }
  return make_float4((mn0+mx0)*0.5f, (mn1+mx1)*0.5f, (mn2+mx2)*0.5f,
                     1.8f/fmaxf(mx0-mn0, fmaxf(mx1-mn1, mx2-mn2)));
}

__device__ __forceinline__ void transform_one(
    const float* __restrict__ xyz, const float* __restrict__ scal,
    const float* __restrict__ rot, const float* __restrict__ opac,
    int g, float cx, float cy, float cz, float sc, float4* __restrict__ rec)
{
  float o = opac[g];
  float sig = 1.0f/(1.0f + __expf(-o));
  float opa = (sig > 0.005f) ? sig : 0.0f;
  float xs = (xyz[3*g+0]-cx)*sc;
  float ys = (xyz[3*g+1]-cy)*sc;
  float zs = (xyz[3*g+2]-cz)*sc;
  float sdx = __expf(scal[3*g+0])*sc;
  float sdy = __expf(scal[3*g+1])*sc;
  float sdz = __expf(scal[3*g+2])*sc;
  float qr=rot[4*g+0], qx=rot[4*g+1], qy=rot[4*g+2], qz=rot[4*g+3];
  float qn = 1.0f/sqrtf(qr*qr+qx*qx+qy*qy+qz*qz);
  qr*=qn; qx*=qn; qy*=qn; qz*=qn;
  float R00 = 1.0f-2.0f*(qy*qy+qz*qz), R01 = 2.0f*(qx*qy-qr*qz), R02 = 2.0f*(qx*qz+qr*qy);
  float R10 = 2.0f*(qx*qy+qr*qz), R11 = 1.0f-2.0f*(qx*qx+qz*qz), R12 = 2.0f*(qy*qz-qr*qx);
  float R20 = 2.0f*(qx*qz-qr*qy), R21 = 2.0f*(qy*qz+qr*qx), R22 = 1.0f-2.0f*(qx*qx+qy*qy);
  float L00=R00*sdx, L01=R01*sdy, L02=R02*sdz;
  float L10=R10*sdx, L11=R11*sdy, L12=R12*sdz;
  float L20=R20*sdx, L21=R21*sdy, L22=R22*sdz;
  float a = L00*L00+L01*L01+L02*L02;
  float bb= L00*L10+L01*L11+L02*L12;
  float cc= L00*L20+L01*L21+L02*L22;
  float d = L10*L10+L11*L11+L12*L12;
  float e = L10*L20+L11*L21+L12*L22;
  float f = L20*L20+L21*L21+L22*L22;
  float det = a*d*f + 2.0f*e*cc*bb - e*e*a - cc*cc*d - bb*bb*f + 1e-24f;
  float idt = 1.0f/det;
  float ia=(d*f-e*e)*idt, ib=(e*cc-bb*f)*idt, ic=(e*bb-cc*d)*idt;
  float id=(a*f-cc*cc)*idt, ie=(bb*cc-e*a)*idt, iff=(a*d-bb*bb)*idt;
  rec[3*g+0] = make_float4(xs, ys, zs, opa);
  rec[3*g+1] = make_float4(-0.5f*ia, -ib, -ic, -0.5f*id);
  rec[3*g+2] = make_float4(-ie, -0.5f*iff, 0.0f, 0.0f);
}

template<int T>
__device__ __forceinline__ void bin_column(
    const float4* __restrict__ xyz4, const float4* __restrict__ op4,
    int c, int tid, float cx, float cy, float cz, float sc,
    int* s_cnt, unsigned short* __restrict__ binidx)
{
  const int bi = c >> 4, bj = c & 15;
  const float vminx = linf(bi*4) - RELAX, vmaxx = linf(bi*4+3) + RELAX;
  const float vminy = linf(bj*4) - RELAX, vmaxy = linf(bj*4+3) + RELAX;
  #pragma unroll
  for (int t = 0; t < NG/4/T; ++t) {
    const int G = t*T + tid;
    float4 v0 = xyz4[3*G+0], v1 = xyz4[3*G+1], v2 = xyz4[3*G+2];
    float4 oo = op4[G];
    float gx[4] = {v0.x, v0.w, v1.z, v2.y};
    float gy[4] = {v0.y, v1.x, v1.w, v2.z};
    float gz[4] = {v0.z, v1.y, v2.x, v2.w};
    float go[4] = {oo.x, oo.y, oo.z, oo.w};
    #pragma unroll
    for (int u = 0; u < 4; ++u) {
      if (!(go[u] > KEEPTH)) continue;
      float xs = (gx[u]-cx)*sc;
      float ys = (gy[u]-cy)*sc;
      float zs = (gz[u]-cz)*sc;
      if (xs > vminx && xs < vmaxx && ys > vminy && ys < vmaxy) {
        int klo = (int)floorf(((zs + 0.8125f)*31.5f - 3.0f)*0.25f) - 1;
        int khi = (int)floorf((zs + 1.1875f)*7.875f) + 1;
        klo = max(klo, 0); khi = min(khi, 15);
        for (int bk = klo; bk <= khi; ++bk) {
          float lo = linf(bk*4) - RELAX, hi = linf(bk*4+3) + RELAX;
          if (zs > lo && zs < hi) {
            int slot = atomicAdd(&s_cnt[bk], 1);
            if (slot < CAP)
              binidx[(size_t)((c<<4) + bk)*CAP + slot] = (unsigned short)(4*G+u);
          }
        }
      }
    }
  }
}

// ======================================================================
// A: prep+bin.  256 blocks x 512 thr (2 blocks/CU, 8 waves -> 2x the
// latency hiding of every previous prep).  LDS counters (no global
// contention), verified math throughout.
// ======================================================================
__global__ __launch_bounds__(512) void gm_prep_bin(
    const float* __restrict__ xyz, const float* __restrict__ scal,
    const float* __restrict__ rot, const float* __restrict__ opac,
    float4* __restrict__ rec,
    int* __restrict__ bincnt, unsigned short* __restrict__ binidx)
{
  __shared__ float s_r[8][6];
  __shared__ int   s_cnt[16];
  const int tid = threadIdx.x;
  const int b   = blockIdx.x;            // column bi*16+bj
  const float4* xyz4 = (const float4*)xyz;
  const float4* op4  = (const float4*)opac;
  if (tid < 16) s_cnt[tid] = 0;
  const float4 cs = block_minmax_cs<512>(xyz4, op4, tid, s_r);   // has barrier
  const float cx = cs.x, cy = cs.y, cz = cs.z, sc = cs.w;
  if (tid < 16) transform_one(xyz, scal, rot, opac, b*16+tid, cx, cy, cz, sc, rec);
  bin_column<512>(xyz4, op4, b, tid, cx, cy, cz, sc, s_cnt, binidx);
  __syncthreads();
  if (tid < 16) bincnt[(b<<4) + tid] = min(s_cnt[tid], CAP);
}

// ======================================================================
// B: wave-autonomous eval.  1024 blocks x 1024 thr (16 waves).
// wave_gid = b*16+w; quartile kq=w>>2, rank = kq*1024 + b (centrality
// strata, decorrelated per block); bin = cperm3(rank); split s=w&3
// (records j = s, s+4, ...).  Lane = voxel: 100% lane occupancy, record
// index wave-uniform -> broadcast loads, ZERO barriers in record loop,
// no LDS staging, no atomics.  4-way partials merge via 4KB LDS + one
// barrier; direct store (every bin covered exactly once -> no out-zero).
// ======================================================================
__global__ __launch_bounds__(1024) void gm_eval_wave(
    const float4* __restrict__ rec,
    const int* __restrict__ bincnt, const unsigned short* __restrict__ binidx,
    float* __restrict__ out)
{
  __shared__ float s_p[16][64];         // 4 KB
  const int tid = threadIdx.x;
  const int w   = tid >> 6;             // wave 0..15
  const int p   = tid & 63;             // lane = voxel
  const int b   = blockIdx.x;
  const int kq  = w >> 2;               // quartile stratum 0..3
  const int s   = w & 3;                // record split
  const int rank = kq*1024 + b;         // heavy-first rank
  const int bi = cperm(rank >> 8), bj = cperm((rank >> 4) & 15), bk = cperm(rank & 15);
  const int bin = (bi*16 + bj)*16 + bk;
  const int sx = p >> 4, sy = (p >> 2) & 3, sz = p & 3;
  const float ptx = linf(bi*4+sx), pty = linf(bj*4+sy), ptz = linf(bk*4+sz);
  const int n = min(bincnt[bin], CAP);
  const unsigned short* lst = binidx + (size_t)bin*CAP;

  float acc = 0.0f;
  #pragma unroll 2
  for (int j = s; j < n; j += 4) {
    const int g = __builtin_amdgcn_readfirstlane((int)lst[j]);  // uniform -> SGPR
    float4 P  = rec[3*g+0];
    float4 I0 = rec[3*g+1];
    float4 I1 = rec[3*g+2];
    float px = ptx - P.x, py = pty - P.y, pz = ptz - P.z;
    float power = px*px*I0.x + py*py*I0.w + pz*pz*I1.y
                + px*py*I0.y + px*pz*I0.z + py*pz*I1.x;
    power = (power > 0.0f) ? -1e10f : power;   // branchless
    acc += P.w * __expf(power);
  }
  s_p[w][p] = acc;
  __syncthreads();                       // single barrier in the kernel
  if (s == 0) {
    const float v = s_p[w][p] + s_p[w+1][p] + s_p[w+2][p] + s_p[w+3][p];
    out[(bi*4+sx)*4096 + (bj*4+sy)*64 + (bk*4+sz)] = v;
  }
}

// ======================================================================
// Fallback (tiny ws): fully fused, zero-workspace (r4/r6-verified)
// ======================================================================
__global__ __launch_bounds__(256) void gm_fused_nows(
    const float* __restrict__ xyz, const float* __restrict__ scal,
    const float* __restrict__ rot, const float* __restrict__ opac,
    float* __restrict__ out)
{
  __shared__ float s_r[8][6];
  __shared__ float4 s_g[256*3];
  __shared__ float  s_acc[256];
  __shared__ int    s_cnt;
  const int tid = threadIdx.x;
  const float4* xyz4 = (const float4*)xyz;
  const float4* op4  = (const float4*)opac;
  if (tid == 0) s_cnt = 0;
  const float4 cs = block_minmax_cs<256>(xyz4, op4, tid, s_r);
  const float cx = cs.x, cy = cs.y, cz = cs.z, sc = cs.w;

  const int bin = blockIdx.x;
  const int bi = bin >> 8, bj = (bin >> 4) & 15, bk = bin & 15;
  const float vminx = linf(bi*4) - RELAX, vmaxx = linf(bi*4+3) + RELAX;
  const float vminy = linf(bj*4) - RELAX, vmaxy = linf(bj*4+3) + RELAX;
  const float vminz = linf(bk*4) - RELAX, vmaxz = linf(bk*4+3) + RELAX;
  const int p    = tid & 63;
  const int part = tid >> 6;
  const int sx = p >> 4, sy = (p >> 2) & 3, sz = p & 3;
  const float ptx = linf(bi*4+sx), pty = linf(bj*4+sy), ptz = linf(bk*4+sz);
  float acc = 0.0f;
  __syncthreads();

  for (int c0 = 0; c0 < NG; c0 += 256) {
    const int g = c0 + tid;
    float o = opac[g];
    bool pass = false;
    float xs=0, ys=0, zs=0, sig=0;
    if (o > KEEPTH) {
      sig = 1.0f/(1.0f + __expf(-o));
      xs = (xyz[3*g+0]-cx)*sc;
      ys = (xyz[3*g+1]-cy)*sc;
      zs = (xyz[3*g+2]-cz)*sc;
      pass = xs > vminx && xs < vmaxx &&
             ys > vminy && ys < vmaxy &&
             zs > vminz && zs < vmaxz;
    }
    if (pass) {
      float sdx = __expf(scal[3*g+0])*sc;
      float sdy = __expf(scal[3*g+1])*sc;
      float sdz = __expf(scal[3*g+2])*sc;
      float qr=rot[4*g+0], qx=rot[4*g+1], qy=rot[4*g+2], qz=rot[4*g+3];
      float qn = 1.0f/sqrtf(qr*qr+qx*qx+qy*qy+qz*qz);
      qr*=qn; qx*=qn; qy*=qn; qz*=qn;
      float R00 = 1.0f-2.0f*(qy*qy+qz*qz), R01 = 2.0f*(qx*qy-qr*qz), R02 = 2.0f*(qx*qz+qr*qy);
      float R10 = 2.0f*(qx*qy+qr*qz), R11 = 1.0f-2.0f*(qx*qx+qz*qz), R12 = 2.0f*(qy*qz-qr*qx);
      float R20 = 2.0f*(qx*qz-qr*qy), R21 = 2.0f*(qy*qz+qr*qx), R22 = 1.0f-2.0f*(qx*qx+qy*qy);
      float L00=R00*sdx, L01=R01*sdy, L02=R02*sdz;
      float L10=R10*sdx, L11=R11*sdy, L12=R12*sdz;
      float L20=R20*sdx, L21=R21*sdy, L22=R22*sdz;
      float a = L00*L00+L01*L01+L02*L02;
      float bb= L00*L10+L01*L11+L02*L12;
      float cc= L00*L20+L01*L21+L02*L22;
      float d = L10*L10+L11*L11+L12*L12;
      float e = L10*L20+L11*L21+L12*L22;
      float f = L20*L20+L21*L21+L22*L22;
      float det = a*d*f + 2.0f*e*cc*bb - e*e*a - cc*cc*d - bb*bb*f + 1e-24f;
      float idt = 1.0f/det;
      float ia=(d*f-e*e)*idt, ib=(e*cc-bb*f)*idt, ic=(e*bb-cc*d)*idt;
      float id=(a*f-cc*cc)*idt, ie=(bb*cc-e*a)*idt, iff=(a*d-bb*bb)*idt;
      int slot = atomicAdd(&s_cnt, 1);
      s_g[3*slot+0] = make_float4(xs, ys, zs, sig);
      s_g[3*slot+1] = make_float4(-0.5f*ia, -ib, -ic, -0.5f*id);
      s_g[3*slot+2] = make_float4(-ie, -0.5f*iff, 0.0f, 0.0f);
    }
    __syncthreads();
    const int nn = s_cnt;
    #pragma unroll 4
    for (int j = part; j < nn; j += 4) {
      float4 P  = s_g[3*j+0];
      float4 I0 = s_g[3*j+1];
      float4 I1 = s_g[3*j+2];
      float px = ptx - P.x, py = pty - P.y, pz = ptz - P.z;
      float power = px*px*I0.x + py*py*I0.w + pz*pz*I1.y
                  + px*py*I0.y + px*pz*I0.z + py*pz*I1.x;
      power = (power > 0.0f) ? -1e10f : power;
      acc += P.w * __expf(power);
    }
    __syncthreads();
    if (tid == 0) s_cnt = 0;
    __syncthreads();
  }
  s_acc[tid] = acc;
  __syncthreads();
  if (tid < 64) {
    float v = s_acc[tid] + s_acc[tid+64] + s_acc[tid+128] + s_acc[tid+192];
    out[(bi*4+sx)*4096 + (bj*4+sy)*64 + (bk*4+sz)] = v;
  }
}

extern "C" void kernel_launch(void* const* d_in, const int* in_sizes, int n_in,
                              void* d_out, int out_size, void* d_ws, size_t ws_size,
                              hipStream_t stream) {
  const float* xyz  = (const float*)d_in[0];
  const float* scal = (const float*)d_in[1];
  const float* rot  = (const float*)d_in[2];
  const float* opac = (const float*)d_in[3];
  float* out = (float*)d_out;
  char* ws = (char*)d_ws;
  float4* rec    = (float4*)ws;                 // 192 KB (P,I0,I1) x 4096
  int*    bincnt = (int*)(ws + 196608);         //  16 KB (4096 bins)
  unsigned short* binidx = (unsigned short*)(ws + 196608 + 16384);
  const size_t base = 196608 + 16384;

  if (ws_size >= base + (size_t)4096*CAP*2) {
    gm_prep_bin<<<256, 512, 0, stream>>>(xyz, scal, rot, opac,
                                         rec, bincnt, binidx);
    gm_eval_wave<<<1024, 1024, 0, stream>>>(rec, bincnt, binidx, out);
  } else {
    gm_fused_nows<<<4096, 256, 0, stream>>>(xyz, scal, rot, opac, out);
  }
}

// Round 9
// 121.923 us; speedup vs baseline: 3.9141x; 1.1959x over previous
//
#include <hip/hip_runtime.h>

#define NG 4096
#define RELAX 0.1875f
#define KEEPTH -5.2933049f   // logit(0.005): sigmoid(o)>0.005 <=> o>KEEPTH

__device__ __forceinline__ float linf(int i) { return -1.0f + (2.0f/63.0f)*(float)i; }
// center-first axis permutation: {7,8,6,9,5,10,4,11,3,12,2,13,1,14,0,15}
__device__ __forceinline__ int cperm(int i) { return (i & 1) ? 7 + ((i+1)>>1) : 7 - (i>>1); }

// ---- shared device helpers (math verified r3-r8) ----
template<int T>
__device__ __forceinline__ float4 block_minmax_cs(
    const float4* __restrict__ xyz4, const float4* __restrict__ op4,
    int tid, float (*s_r)[6])
{
  float mn0=1e10f, mn1=1e10f, mn2=1e10f;
  float mx0=-1e10f, mx1=-1e10f, mx2=-1e10f;
  #pragma unroll
  for (int t = 0; t < NG/4/T; ++t) {
    const int G = t*T + tid;             // group of 4 gaussians
    float4 v0 = xyz4[3*G+0], v1 = xyz4[3*G+1], v2 = xyz4[3*G+2];
    float4 oo = op4[G];
    if (oo.x > KEEPTH) { mn0=fminf(mn0,v0.x); mx0=fmaxf(mx0,v0.x);
                         mn1=fminf(mn1,v0.y); mx1=fmaxf(mx1,v0.y);
                         mn2=fminf(mn2,v0.z); mx2=fmaxf(mx2,v0.z); }
    if (oo.y > KEEPTH) { mn0=fminf(mn0,v0.w); mx0=fmaxf(mx0,v0.w);
                         mn1=fminf(mn1,v1.x); mx1=fmaxf(mx1,v1.x);
                         mn2=fminf(mn2,v1.y); mx2=fmaxf(mx2,v1.y); }
    if (oo.z > KEEPTH) { mn0=fminf(mn0,v1.z); mx0=fmaxf(mx0,v1.z);
                         mn1=fminf(mn1,v1.w); mx1=fmaxf(mx1,v1.w);
                         mn2=fminf(mn2,v2.x); mx2=fmaxf(mx2,v2.x); }
    if (oo.w > KEEPTH) { mn0=fminf(mn0,v2.y); mx0=fmaxf(mx0,v2.y);
                         mn1=fminf(mn1,v2.z); mx1=fmaxf(mx1,v2.z);
                         mn2=fminf(mn2,v2.w); mx2=fmaxf(mx2,v2.w); }
  }
  #pragma unroll
  for (int s = 1; s < 64; s <<= 1) {
    mn0 = fminf(mn0, __shfl_xor(mn0, s)); mx0 = fmaxf(mx0, __shfl_xor(mx0, s));
    mn1 = fminf(mn1, __shfl_xor(mn1, s)); mx1 = fmaxf(mx1, __shfl_xor(mx1, s));
    mn2 = fminf(mn2, __shfl_xor(mn2, s)); mx2 = fmaxf(mx2, __shfl_xor(mx2, s));
  }
  if ((tid & 63) == 0) {
    const int w = tid >> 6;
    s_r[w][0]=mn0; s_r[w][1]=mn1; s_r[w][2]=mn2;
    s_r[w][3]=mx0; s_r[w][4]=mx1; s_r[w][5]=mx2;
  }
  __syncthreads();
  mn0 = s_r[0][0]; mn1 = s_r[0][1]; mn2 = s_r[0][2];
  mx0 = s_r[0][3]; mx1 = s_r[0][4]; mx2 = s_r[0][5];
  #pragma unroll
  for (int w = 1; w < T/64; ++w) {
    mn0 = fminf(mn0, s_r[w][0]); mn1 = fminf(mn1, s_r[w][1]); mn2 = fminf(mn2, s_r[w][2]);
    mx0 = fmaxf(mx0, s_r[w][3]); mx1 = fmaxf(mx1, s_r[w][4]); mx2 = fmaxf(mx2, s_r[w][5]);
  }
  return make_float4((mn0+mx0)*0.5f, (mn1+mx1)*0.5f, (mn2+mx2)*0.5f,
                     1.8f/fmaxf(mx0-mn0, fmaxf(mx1-mn1, mx2-mn2)));
}

__device__ __forceinline__ void transform_one(
    const float* __restrict__ xyz, const float* __restrict__ scal,
    const float* __restrict__ rot, const float* __restrict__ opac,
    int g, float cx, float cy, float cz, float sc, float4* __restrict__ rec)
{
  float o = opac[g];
  float sig = 1.0f/(1.0f + __expf(-o));
  float opa = (sig > 0.005f) ? sig : 0.0f;
  float xs = (xyz[3*g+0]-cx)*sc;
  float ys = (xyz[3*g+1]-cy)*sc;
  float zs = (xyz[3*g+2]-cz)*sc;
  float sdx = __expf(scal[3*g+0])*sc;
  float sdy = __expf(scal[3*g+1])*sc;
  float sdz = __expf(scal[3*g+2])*sc;
  float qr=rot[4*g+0], qx=rot[4*g+1], qy=rot[4*g+2], qz=rot[4*g+3];
  float qn = 1.0f/sqrtf(qr*qr+qx*qx+qy*qy+qz*qz);
  qr*=qn; qx*=qn; qy*=qn; qz*=qn;
  float R00 = 1.0f-2.0f*(qy*qy+qz*qz), R01 = 2.0f*(qx*qy-qr*qz), R02 = 2.0f*(qx*qz+qr*qy);
  float R10 = 2.0f*(qx*qy+qr*qz), R11 = 1.0f-2.0f*(qx*qx+qz*qz), R12 = 2.0f*(qy*qz-qr*qx);
  float R20 = 2.0f*(qx*qz-qr*qy), R21 = 2.0f*(qy*qz+qr*qx), R22 = 1.0f-2.0f*(qx*qx+qy*qy);
  float L00=R00*sdx, L01=R01*sdy, L02=R02*sdz;
  float L10=R10*sdx, L11=R11*sdy, L12=R12*sdz;
  float L20=R20*sdx, L21=R21*sdy, L22=R22*sdz;
  float a = L00*L00+L01*L01+L02*L02;
  float bb= L00*L10+L01*L11+L02*L12;
  float cc= L00*L20+L01*L21+L02*L22;
  float d = L10*L10+L11*L11+L12*L12;
  float e = L10*L20+L11*L21+L12*L22;
  float f = L20*L20+L21*L21+L22*L22;
  float det = a*d*f + 2.0f*e*cc*bb - e*e*a - cc*cc*d - bb*bb*f + 1e-24f;
  float idt = 1.0f/det;
  float ia=(d*f-e*e)*idt, ib=(e*cc-bb*f)*idt, ic=(e*bb-cc*d)*idt;
  float id=(a*f-cc*cc)*idt, ie=(bb*cc-e*a)*idt, iff=(a*d-bb*bb)*idt;
  rec[3*g+0] = make_float4(xs, ys, zs, opa);
  rec[3*g+1] = make_float4(-0.5f*ia, -ib, -ic, -0.5f*id);
  rec[3*g+2] = make_float4(-ie, -0.5f*iff, 0.0f, 0.0f);
}

// ======================================================================
// A: prep only (no binning!).  256 blocks x 256 thr.
// Redundant minmax (L2-resident, identical per block) + transform 16
// gaussians per block into packed rec[] (48 B/gaussian).
// ======================================================================
__global__ __launch_bounds__(256) void gm_prep(
    const float* __restrict__ xyz, const float* __restrict__ scal,
    const float* __restrict__ rot, const float* __restrict__ opac,
    float4* __restrict__ rec)
{
  __shared__ float s_r[8][6];
  const int tid = threadIdx.x;
  const int b   = blockIdx.x;
  const float4* xyz4 = (const float4*)xyz;
  const float4* op4  = (const float4*)opac;
  const float4 cs = block_minmax_cs<256>(xyz4, op4, tid, s_r);
  if (tid < 16)
    transform_one(xyz, scal, rot, opac, b*16+tid, cs.x, cs.y, cs.z, cs.w, rec);
}

// ======================================================================
// B: eval.  4096 blocks (= bins, cperm heavy-first) x 512 thr (8 waves).
// Wave w scans gaussian slice [w*512,(w+1)*512) in 8 sub-chunks of 64:
//   one PARALLEL 16B load/lane -> window test -> ballot/popc compact into
//   per-wave LDS (no atomics, no barriers, wave-synchronous) -> evaluate
//   lane=voxel over m<=64 records via LDS broadcast reads.
// Merge 8 wave partials through LDS (single __syncthreads), direct store.
// No bin lists, no global atomics, no out pre-zero.
// ======================================================================
__global__ __launch_bounds__(512) void gm_eval(
    const float4* __restrict__ rec, float* __restrict__ out)
{
  __shared__ float4 s_g[8][64*3];       // 24 KB: per-wave staging
  __shared__ float  s_p[8][64];         //  2 KB: partials
  const int tid  = threadIdx.x;
  const int w    = tid >> 6;            // wave 0..7
  const int lane = tid & 63;            // lane = voxel
  const int b = blockIdx.x;
  const int bi = cperm(b >> 8), bj = cperm((b >> 4) & 15), bk = cperm(b & 15);
  const float vminx = linf(bi*4) - RELAX, vmaxx = linf(bi*4+3) + RELAX;
  const float vminy = linf(bj*4) - RELAX, vmaxy = linf(bj*4+3) + RELAX;
  const float vminz = linf(bk*4) - RELAX, vmaxz = linf(bk*4+3) + RELAX;
  const int sx = lane >> 4, sy = (lane >> 2) & 3, sz = lane & 3;
  const float ptx = linf(bi*4+sx), pty = linf(bj*4+sy), ptz = linf(bk*4+sz);
  float acc = 0.0f;

  #pragma unroll
  for (int scn = 0; scn < 8; ++scn) {
    const int g = w*512 + scn*64 + lane;
    const float4 P = rec[3*g+0];                         // parallel 16B load
    const bool pass = (P.w > 0.0f &&
                       P.x > vminx && P.x < vmaxx &&
                       P.y > vminy && P.y < vmaxy &&
                       P.z > vminz && P.z < vmaxz);
    const unsigned long long mask = __ballot(pass);
    const int m = __popcll(mask);
    if (m == 0) continue;
    if (pass) {
      const int slot = __popcll(mask & ((1ull << lane) - 1ull));
      s_g[w][3*slot+0] = P;
      s_g[w][3*slot+1] = rec[3*g+1];                     // survivors only
      s_g[w][3*slot+2] = rec[3*g+2];
    }
    __builtin_amdgcn_wave_barrier();    // scheduling fence (wave-sync LDS)
    for (int j = 0; j < m; ++j) {
      float4 Pq = s_g[w][3*j+0];        // uniform addr -> LDS broadcast
      float4 I0 = s_g[w][3*j+1];
      float4 I1 = s_g[w][3*j+2];
      float px = ptx - Pq.x, py = pty - Pq.y, pz = ptz - Pq.z;
      float power = px*px*I0.x + py*py*I0.w + pz*pz*I1.y
                  + px*py*I0.y + px*pz*I0.z + py*pz*I1.x;
      power = (power > 0.0f) ? -1e10f : power;           // branchless
      acc += Pq.w * __expf(power);
    }
    __builtin_amdgcn_wave_barrier();    // writes of next scn vs reads above
  }

  s_p[w][lane] = acc;
  __syncthreads();                      // the only block barrier
  if (w == 0) {
    float v = 0.0f;
    #pragma unroll
    for (int q = 0; q < 8; ++q) v += s_p[q][lane];
    out[(bi*4+sx)*4096 + (bj*4+sy)*64 + (bk*4+sz)] = v;
  }
}

// ======================================================================
// Fallback (ws too small for 192 KB): fully fused, zero-workspace
// (r4/r6-verified).
// ======================================================================
__global__ __launch_bounds__(256) void gm_fused_nows(
    const float* __restrict__ xyz, const float* __restrict__ scal,
    const float* __restrict__ rot, const float* __restrict__ opac,
    float* __restrict__ out)
{
  __shared__ float s_r[8][6];
  __shared__ float4 s_g[256*3];
  __shared__ float  s_acc[256];
  __shared__ int    s_cnt;
  const int tid = threadIdx.x;
  const float4* xyz4 = (const float4*)xyz;
  const float4* op4  = (const float4*)opac;
  if (tid == 0) s_cnt = 0;
  const float4 cs = block_minmax_cs<256>(xyz4, op4, tid, s_r);
  const float cx = cs.x, cy = cs.y, cz = cs.z, sc = cs.w;

  const int bin = blockIdx.x;
  const int bi = bin >> 8, bj = (bin >> 4) & 15, bk = bin & 15;
  const float vminx = linf(bi*4) - RELAX, vmaxx = linf(bi*4+3) + RELAX;
  const float vminy = linf(bj*4) - RELAX, vmaxy = linf(bj*4+3) + RELAX;
  const float vminz = linf(bk*4) - RELAX, vmaxz = linf(bk*4+3) + RELAX;
  const int p    = tid & 63;
  const int part = tid >> 6;
  const int sx = p >> 4, sy = (p >> 2) & 3, sz = p & 3;
  const float ptx = linf(bi*4+sx), pty = linf(bj*4+sy), ptz = linf(bk*4+sz);
  float acc = 0.0f;
  __syncthreads();

  for (int c0 = 0; c0 < NG; c0 += 256) {
    const int g = c0 + tid;
    float o = opac[g];
    bool pass = false;
    float xs=0, ys=0, zs=0, sig=0;
    if (o > KEEPTH) {
      sig = 1.0f/(1.0f + __expf(-o));
      xs = (xyz[3*g+0]-cx)*sc;
      ys = (xyz[3*g+1]-cy)*sc;
      zs = (xyz[3*g+2]-cz)*sc;
      pass = xs > vminx && xs < vmaxx &&
             ys > vminy && ys < vmaxy &&
             zs > vminz && zs < vmaxz;
    }
    if (pass) {
      float sdx = __expf(scal[3*g+0])*sc;
      float sdy = __expf(scal[3*g+1])*sc;
      float sdz = __expf(scal[3*g+2])*sc;
      float qr=rot[4*g+0], qx=rot[4*g+1], qy=rot[4*g+2], qz=rot[4*g+3];
      float qn = 1.0f/sqrtf(qr*qr+qx*qx+qy*qy+qz*qz);
      qr*=qn; qx*=qn; qy*=qn; qz*=qn;
      float R00 = 1.0f-2.0f*(qy*qy+qz*qz), R01 = 2.0f*(qx*qy-qr*qz), R02 = 2.0f*(qx*qz+qr*qy);
      float R10 = 2.0f*(qx*qy+qr*qz), R11 = 1.0f-2.0f*(qx*qx+qz*qz), R12 = 2.0f*(qy*qz-qr*qx);
      float R20 = 2.0f*(qx*qz-qr*qy), R21 = 2.0f*(qy*qz+qr*qx), R22 = 1.0f-2.0f*(qx*qx+qy*qy);
      float L00=R00*sdx, L01=R01*sdy, L02=R02*sdz;
      float L10=R10*sdx, L11=R11*sdy, L12=R12*sdz;
      float L20=R20*sdx, L21=R21*sdy, L22=R22*sdz;
      float a = L00*L00+L01*L01+L02*L02;
      float bb= L00*L10+L01*L11+L02*L12;
      float cc= L00*L20+L01*L21+L02*L22;
      float d = L10*L10+L11*L11+L12*L12;
      float e = L10*L20+L11*L21+L12*L22;
      float f = L20*L20+L21*L21+L22*L22;
      float det = a*d*f + 2.0f*e*cc*bb - e*e*a - cc*cc*d - bb*bb*f + 1e-24f;
      float idt = 1.0f/det;
      float ia=(d*f-e*e)*idt, ib=(e*cc-bb*f)*idt, ic=(e*bb-cc*d)*idt;
      float id=(a*f-cc*cc)*idt, ie=(bb*cc-e*a)*idt, iff=(a*d-bb*bb)*idt;
      int slot = atomicAdd(&s_cnt, 1);
      s_g[3*slot+0] = make_float4(xs, ys, zs, sig);
      s_g[3*slot+1] = make_float4(-0.5f*ia, -ib, -ic, -0.5f*id);
      s_g[3*slot+2] = make_float4(-ie, -0.5f*iff, 0.0f, 0.0f);
    }
    __syncthreads();
    const int nn = s_cnt;
    #pragma unroll 4
    for (int j = part; j < nn; j += 4) {
      float4 P  = s_g[3*j+0];
      float4 I0 = s_g[3*j+1];
      float4 I1 = s_g[3*j+2];
      float px = ptx - P.x, py = pty - P.y, pz = ptz - P.z;
      float power = px*px*I0.x + py*py*I0.w + pz*pz*I1.y
                  + px*py*I0.y + px*pz*I0.z + py*pz*I1.x;
      power = (power > 0.0f) ? -1e10f : power;
      acc += P.w * __expf(power);
    }
    __syncthreads();
    if (tid == 0) s_cnt = 0;
    __syncthreads();
  }
  s_acc[tid] = acc;
  __syncthreads();
  if (tid < 64) {
    float v = s_acc[tid] + s_acc[tid+64] + s_acc[tid+128] + s_acc[tid+192];
    out[(bi*4+sx)*4096 + (bj*4+sy)*64 + (bk*4+sz)] = v;
  }
}

extern "C" void kernel_launch(void* const* d_in, const int* in_sizes, int n_in,
                              void* d_out, int out_size, void* d_ws, size_t ws_size,
                              hipStream_t stream) {
  const float* xyz  = (const float*)d_in[0];
  const float* scal = (const float*)d_in[1];
  const float* rot  = (const float*)d_in[2];
  const float* opac = (const float*)d_in[3];
  float* out = (float*)d_out;
  float4* rec = (float4*)d_ws;                  // 192 KB (P,I0,I1) x 4096

  if (ws_size >= 196608) {
    gm_prep<<<256, 256, 0, stream>>>(xyz, scal, rot, opac, rec);
    gm_eval<<<4096, 512, 0, stream>>>(rec, out);
  } else {
    gm_fused_nows<<<4096, 256, 0, stream>>>(xyz, scal, rot, opac, out);
  }
}

// Round 10
// 111.977 us; speedup vs baseline: 4.2617x; 1.0888x over previous
//
#include <hip/hip_runtime.h>

#define NG 4096
#define RELAX 0.1875f
#define KEEPTH -5.2933049f   // logit(0.005): sigmoid(o)>0.005 <=> o>KEEPTH

__device__ __forceinline__ float linf(int i) { return -1.0f + (2.0f/63.0f)*(float)i; }
// center-first axis permutation: {7,8,6,9,5,10,4,11,3,12,2,13,1,14,0,15}
__device__ __forceinline__ int cperm(int i) { return (i & 1) ? 7 + ((i+1)>>1) : 7 - (i>>1); }

// ---- shared device helpers (math verified r3-r9) ----
template<int T>
__device__ __forceinline__ float4 block_minmax_cs(
    const float4* __restrict__ xyz4, const float4* __restrict__ op4,
    int tid, float (*s_r)[6])
{
  float mn0=1e10f, mn1=1e10f, mn2=1e10f;
  float mx0=-1e10f, mx1=-1e10f, mx2=-1e10f;
  #pragma unroll
  for (int t = 0; t < NG/4/T; ++t) {
    const int G = t*T + tid;             // group of 4 gaussians
    float4 v0 = xyz4[3*G+0], v1 = xyz4[3*G+1], v2 = xyz4[3*G+2];
    float4 oo = op4[G];
    if (oo.x > KEEPTH) { mn0=fminf(mn0,v0.x); mx0=fmaxf(mx0,v0.x);
                         mn1=fminf(mn1,v0.y); mx1=fmaxf(mx1,v0.y);
                         mn2=fminf(mn2,v0.z); mx2=fmaxf(mx2,v0.z); }
    if (oo.y > KEEPTH) { mn0=fminf(mn0,v0.w); mx0=fmaxf(mx0,v0.w);
                         mn1=fminf(mn1,v1.x); mx1=fmaxf(mx1,v1.x);
                         mn2=fminf(mn2,v1.y); mx2=fmaxf(mx2,v1.y); }
    if (oo.z > KEEPTH) { mn0=fminf(mn0,v1.z); mx0=fmaxf(mx0,v1.z);
                         mn1=fminf(mn1,v1.w); mx1=fmaxf(mx1,v1.w);
                         mn2=fminf(mn2,v2.x); mx2=fmaxf(mx2,v2.x); }
    if (oo.w > KEEPTH) { mn0=fminf(mn0,v2.y); mx0=fmaxf(mx0,v2.y);
                         mn1=fminf(mn1,v2.z); mx1=fmaxf(mx1,v2.z);
                         mn2=fminf(mn2,v2.w); mx2=fmaxf(mx2,v2.w); }
  }
  #pragma unroll
  for (int s = 1; s < 64; s <<= 1) {
    mn0 = fminf(mn0, __shfl_xor(mn0, s)); mx0 = fmaxf(mx0, __shfl_xor(mx0, s));
    mn1 = fminf(mn1, __shfl_xor(mn1, s)); mx1 = fmaxf(mx1, __shfl_xor(mx1, s));
    mn2 = fminf(mn2, __shfl_xor(mn2, s)); mx2 = fmaxf(mx2, __shfl_xor(mx2, s));
  }
  if ((tid & 63) == 0) {
    const int w = tid >> 6;
    s_r[w][0]=mn0; s_r[w][1]=mn1; s_r[w][2]=mn2;
    s_r[w][3]=mx0; s_r[w][4]=mx1; s_r[w][5]=mx2;
  }
  __syncthreads();
  mn0 = s_r[0][0]; mn1 = s_r[0][1]; mn2 = s_r[0][2];
  mx0 = s_r[0][3]; mx1 = s_r[0][4]; mx2 = s_r[0][5];
  #pragma unroll
  for (int w = 1; w < T/64; ++w) {
    mn0 = fminf(mn0, s_r[w][0]); mn1 = fminf(mn1, s_r[w][1]); mn2 = fminf(mn2, s_r[w][2]);
    mx0 = fmaxf(mx0, s_r[w][3]); mx1 = fmaxf(mx1, s_r[w][4]); mx2 = fmaxf(mx2, s_r[w][5]);
  }
  return make_float4((mn0+mx0)*0.5f, (mn1+mx1)*0.5f, (mn2+mx2)*0.5f,
                     1.8f/fmaxf(mx0-mn0, fmaxf(mx1-mn1, mx2-mn2)));
}

__device__ __forceinline__ void transform_one(
    const float* __restrict__ xyz, const float* __restrict__ scal,
    const float* __restrict__ rot, const float* __restrict__ opac,
    int g, float cx, float cy, float cz, float sc,
    float4* __restrict__ pos, float4* __restrict__ inv)
{
  float o = opac[g];
  float sig = 1.0f/(1.0f + __expf(-o));
  float opa = (sig > 0.005f) ? sig : 0.0f;
  float xs = (xyz[3*g+0]-cx)*sc;
  float ys = (xyz[3*g+1]-cy)*sc;
  float zs = (xyz[3*g+2]-cz)*sc;
  float sdx = __expf(scal[3*g+0])*sc;
  float sdy = __expf(scal[3*g+1])*sc;
  float sdz = __expf(scal[3*g+2])*sc;
  float qr=rot[4*g+0], qx=rot[4*g+1], qy=rot[4*g+2], qz=rot[4*g+3];
  float qn = 1.0f/sqrtf(qr*qr+qx*qx+qy*qy+qz*qz);
  qr*=qn; qx*=qn; qy*=qn; qz*=qn;
  float R00 = 1.0f-2.0f*(qy*qy+qz*qz), R01 = 2.0f*(qx*qy-qr*qz), R02 = 2.0f*(qx*qz+qr*qy);
  float R10 = 2.0f*(qx*qy+qr*qz), R11 = 1.0f-2.0f*(qx*qx+qz*qz), R12 = 2.0f*(qy*qz-qr*qx);
  float R20 = 2.0f*(qx*qz-qr*qy), R21 = 2.0f*(qy*qz+qr*qx), R22 = 1.0f-2.0f*(qx*qx+qy*qy);
  float L00=R00*sdx, L01=R01*sdy, L02=R02*sdz;
  float L10=R10*sdx, L11=R11*sdy, L12=R12*sdz;
  float L20=R20*sdx, L21=R21*sdy, L22=R22*sdz;
  float a = L00*L00+L01*L01+L02*L02;
  float bb= L00*L10+L01*L11+L02*L12;
  float cc= L00*L20+L01*L21+L02*L22;
  float d = L10*L10+L11*L11+L12*L12;
  float e = L10*L20+L11*L21+L12*L22;
  float f = L20*L20+L21*L21+L22*L22;
  float det = a*d*f + 2.0f*e*cc*bb - e*e*a - cc*cc*d - bb*bb*f + 1e-24f;
  float idt = 1.0f/det;
  float ia=(d*f-e*e)*idt, ib=(e*cc-bb*f)*idt, ic=(e*bb-cc*d)*idt;
  float id=(a*f-cc*cc)*idt, ie=(bb*cc-e*a)*idt, iff=(a*d-bb*bb)*idt;
  pos[g]     = make_float4(xs, ys, zs, opa);
  inv[2*g+0] = make_float4(-0.5f*ia, -ib, -ic, -0.5f*id);
  inv[2*g+1] = make_float4(-ie, -0.5f*iff, 0.0f, 0.0f);
}

// ======================================================================
// A: prep (no binning).  256 blocks x 512 thr (2 blocks/CU, 8 waves/CU).
// Redundant minmax (2-iteration chain at 512 thr) + transform 16
// gaussians per block into SoA pos[] (16B, scan-contiguous) + inv[] (32B).
// ======================================================================
__global__ __launch_bounds__(512) void gm_prep(
    const float* __restrict__ xyz, const float* __restrict__ scal,
    const float* __restrict__ rot, const float* __restrict__ opac,
    float4* __restrict__ pos, float4* __restrict__ inv)
{
  __shared__ float s_r[8][6];
  const int tid = threadIdx.x;
  const int b   = blockIdx.x;
  const float4* xyz4 = (const float4*)xyz;
  const float4* op4  = (const float4*)opac;
  const float4 cs = block_minmax_cs<512>(xyz4, op4, tid, s_r);
  if (tid < 16)
    transform_one(xyz, scal, rot, opac, b*16+tid, cs.x, cs.y, cs.z, cs.w, pos, inv);
}

// ======================================================================
// B: eval.  4096 blocks (= bins, cperm heavy-first) x 512 thr (8 waves).
// Wave w scans its 512-gaussian slice of SoA pos[] in 8 sub-chunks of 64:
//   COALESCED 16B/lane load (contiguous stream) with explicit next-chunk
//   register prefetch (breaks the serial L2-latency chain r9's 32-VGPR
//   allocation revealed) -> window test -> ballot/popc compact into
//   per-wave LDS (survivors gather inv) -> evaluate lane=voxel.
// Merge 8 wave partials via LDS (single __syncthreads), direct store.
// ======================================================================
__global__ __launch_bounds__(512) void gm_eval(
    const float4* __restrict__ pos, const float4* __restrict__ inv,
    float* __restrict__ out)
{
  __shared__ float4 s_g[8][64*3];       // 24 KB: per-wave staging
  __shared__ float  s_p[8][64];         //  2 KB: partials
  const int tid  = threadIdx.x;
  const int w    = tid >> 6;            // wave 0..7
  const int lane = tid & 63;            // lane = voxel
  const int b = blockIdx.x;
  const int bi = cperm(b >> 8), bj = cperm((b >> 4) & 15), bk = cperm(b & 15);
  const float vminx = linf(bi*4) - RELAX, vmaxx = linf(bi*4+3) + RELAX;
  const float vminy = linf(bj*4) - RELAX, vmaxy = linf(bj*4+3) + RELAX;
  const float vminz = linf(bk*4) - RELAX, vmaxz = linf(bk*4+3) + RELAX;
  const int sx = lane >> 4, sy = (lane >> 2) & 3, sz = lane & 3;
  const float ptx = linf(bi*4+sx), pty = linf(bj*4+sy), ptz = linf(bk*4+sz);
  const int gbase = w*512 + lane;
  float acc = 0.0f;

  float4 P = pos[gbase];                // prefetch sub-chunk 0
  #pragma unroll
  for (int scn = 0; scn < 8; ++scn) {
    const int g = gbase + scn*64;
    float4 Pn;
    if (scn < 7) Pn = pos[g + 64];      // prefetch next sub-chunk (in flight
                                        // across compact+eval below)
    const bool pass = (P.w > 0.0f &&
                       P.x > vminx && P.x < vmaxx &&
                       P.y > vminy && P.y < vmaxy &&
                       P.z > vminz && P.z < vmaxz);
    const unsigned long long mask = __ballot(pass);
    const int m = __popcll(mask);
    if (m != 0) {
      if (pass) {
        const int slot = __popcll(mask & ((1ull << lane) - 1ull));
        s_g[w][3*slot+0] = P;
        s_g[w][3*slot+1] = inv[2*g+0];  // survivor-only gather (rare)
        s_g[w][3*slot+2] = inv[2*g+1];
      }
      __builtin_amdgcn_wave_barrier();  // wave-sync LDS (no block barrier)
      for (int j = 0; j < m; ++j) {
        float4 Pq = s_g[w][3*j+0];      // uniform addr -> LDS broadcast
        float4 I0 = s_g[w][3*j+1];
        float4 I1 = s_g[w][3*j+2];
        float px = ptx - Pq.x, py = pty - Pq.y, pz = ptz - Pq.z;
        float power = px*px*I0.x + py*py*I0.w + pz*pz*I1.y
                    + px*py*I0.y + px*pz*I0.z + py*pz*I1.x;
        power = (power > 0.0f) ? -1e10f : power;   // branchless
        acc += Pq.w * __expf(power);
      }
      __builtin_amdgcn_wave_barrier();  // next scn's writes vs reads above
    }
    P = Pn;
  }

  s_p[w][lane] = acc;
  __syncthreads();                      // the only block barrier
  if (w == 0) {
    float v = 0.0f;
    #pragma unroll
    for (int q = 0; q < 8; ++q) v += s_p[q][lane];
    out[(bi*4+sx)*4096 + (bj*4+sy)*64 + (bk*4+sz)] = v;
  }
}

// ======================================================================
// Fallback (ws too small for 192 KB): fully fused, zero-workspace
// (r4/r6-verified).
// ======================================================================
__global__ __launch_bounds__(256) void gm_fused_nows(
    const float* __restrict__ xyz, const float* __restrict__ scal,
    const float* __restrict__ rot, const float* __restrict__ opac,
    float* __restrict__ out)
{
  __shared__ float s_r[8][6];
  __shared__ float4 s_g[256*3];
  __shared__ float  s_acc[256];
  __shared__ int    s_cnt;
  const int tid = threadIdx.x;
  const float4* xyz4 = (const float4*)xyz;
  const float4* op4  = (const float4*)opac;
  if (tid == 0) s_cnt = 0;
  const float4 cs = block_minmax_cs<256>(xyz4, op4, tid, s_r);
  const float cx = cs.x, cy = cs.y, cz = cs.z, sc = cs.w;

  const int bin = blockIdx.x;
  const int bi = bin >> 8, bj = (bin >> 4) & 15, bk = bin & 15;
  const float vminx = linf(bi*4) - RELAX, vmaxx = linf(bi*4+3) + RELAX;
  const float vminy = linf(bj*4) - RELAX, vmaxy = linf(bj*4+3) + RELAX;
  const float vminz = linf(bk*4) - RELAX, vmaxz = linf(bk*4+3) + RELAX;
  const int p    = tid & 63;
  const int part = tid >> 6;
  const int sx = p >> 4, sy = (p >> 2) & 3, sz = p & 3;
  const float ptx = linf(bi*4+sx), pty = linf(bj*4+sy), ptz = linf(bk*4+sz);
  float acc = 0.0f;
  __syncthreads();

  for (int c0 = 0; c0 < NG; c0 += 256) {
    const int g = c0 + tid;
    float o = opac[g];
    bool pass = false;
    float xs=0, ys=0, zs=0, sig=0;
    if (o > KEEPTH) {
      sig = 1.0f/(1.0f + __expf(-o));
      xs = (xyz[3*g+0]-cx)*sc;
      ys = (xyz[3*g+1]-cy)*sc;
      zs = (xyz[3*g+2]-cz)*sc;
      pass = xs > vminx && xs < vmaxx &&
             ys > vminy && ys < vmaxy &&
             zs > vminz && zs < vmaxz;
    }
    if (pass) {
      float sdx = __expf(scal[3*g+0])*sc;
      float sdy = __expf(scal[3*g+1])*sc;
      float sdz = __expf(scal[3*g+2])*sc;
      float qr=rot[4*g+0], qx=rot[4*g+1], qy=rot[4*g+2], qz=rot[4*g+3];
      float qn = 1.0f/sqrtf(qr*qr+qx*qx+qy*qy+qz*qz);
      qr*=qn; qx*=qn; qy*=qn; qz*=qn;
      float R00 = 1.0f-2.0f*(qy*qy+qz*qz), R01 = 2.0f*(qx*qy-qr*qz), R02 = 2.0f*(qx*qz+qr*qy);
      float R10 = 2.0f*(qx*qy+qr*qz), R11 = 1.0f-2.0f*(qx*qx+qz*qz), R12 = 2.0f*(qy*qz-qr*qx);
      float R20 = 2.0f*(qx*qz-qr*qy), R21 = 2.0f*(qy*qz+qr*qx), R22 = 1.0f-2.0f*(qx*qx+qy*qy);
      float L00=R00*sdx, L01=R01*sdy, L02=R02*sdz;
      float L10=R10*sdx, L11=R11*sdy, L12=R12*sdz;
      float L20=R20*sdx, L21=R21*sdy, L22=R22*sdz;
      float a = L00*L00+L01*L01+L02*L02;
      float bb= L00*L10+L01*L11+L02*L12;
      float cc= L00*L20+L01*L21+L02*L22;
      float d = L10*L10+L11*L11+L12*L12;
      float e = L10*L20+L11*L21+L12*L22;
      float f = L20*L20+L21*L21+L22*L22;
      float det = a*d*f + 2.0f*e*cc*bb - e*e*a - cc*cc*d - bb*bb*f + 1e-24f;
      float idt = 1.0f/det;
      float ia=(d*f-e*e)*idt, ib=(e*cc-bb*f)*idt, ic=(e*bb-cc*d)*idt;
      float id=(a*f-cc*cc)*idt, ie=(bb*cc-e*a)*idt, iff=(a*d-bb*bb)*idt;
      int slot = atomicAdd(&s_cnt, 1);
      s_g[3*slot+0] = make_float4(xs, ys, zs, sig);
      s_g[3*slot+1] = make_float4(-0.5f*ia, -ib, -ic, -0.5f*id);
      s_g[3*slot+2] = make_float4(-ie, -0.5f*iff, 0.0f, 0.0f);
    }
    __syncthreads();
    const int nn = s_cnt;
    #pragma unroll 4
    for (int j = part; j < nn; j += 4) {
      float4 P  = s_g[3*j+0];
      float4 I0 = s_g[3*j+1];
      float4 I1 = s_g[3*j+2];
      float px = ptx - P.x, py = pty - P.y, pz = ptz - P.z;
      float power = px*px*I0.x + py*py*I0.w + pz*pz*I1.y
                  + px*py*I0.y + px*pz*I0.z + py*pz*I1.x;
      power = (power > 0.0f) ? -1e10f : power;
      acc += P.w * __expf(power);
    }
    __syncthreads();
    if (tid == 0) s_cnt = 0;
    __syncthreads();
  }
  s_acc[tid] = acc;
  __syncthreads();
  if (tid < 64) {
    float v = s_acc[tid] + s_acc[tid+64] + s_acc[tid+128] + s_acc[tid+192];
    out[(bi*4+sx)*4096 + (bj*4+sy)*64 + (bk*4+sz)] = v;
  }
}

extern "C" void kernel_launch(void* const* d_in, const int* in_sizes, int n_in,
                              void* d_out, int out_size, void* d_ws, size_t ws_size,
                              hipStream_t stream) {
  const float* xyz  = (const float*)d_in[0];
  const float* scal = (const float*)d_in[1];
  const float* rot  = (const float*)d_in[2];
  const float* opac = (const float*)d_in[3];
  float* out = (float*)d_out;
  char* ws = (char*)d_ws;
  float4* pos = (float4*)ws;                    //  64 KB, scan-contiguous
  float4* inv = (float4*)(ws + 65536);          // 128 KB, survivor-gathered

  if (ws_size >= 196608) {
    gm_prep<<<256, 512, 0, stream>>>(xyz, scal, rot, opac, pos, inv);
    gm_eval<<<4096, 512, 0, stream>>>(pos, inv, out);
  } else {
    gm_fused_nows<<<4096, 256, 0, stream>>>(xyz, scal, rot, opac, out);
  }
}